// Round 10
// baseline (310.185 us; speedup 1.0000x reference)
//
#include <hip/hip_runtime.h>

// AdaMoeLayer: B=8,S=4096,D=512,E=8 -> T=32768 tokens
// Round 12: GEMM rebuilt at BK=32 with the A-scale path distributed into
// phase shadows (R10's serial P3 chain was the ~35%-MfmaUtil plateau).
//  - BM=256 BN=256 BK=32, 128 steps, 512 thr (8 waves 2Mx4N), grid 256.
//  - B: global_load_lds ring-3 (48KB), 2-step lookahead, pre-swizzled source.
//  - A: Xbf->reg (issued P0 for s+1) -> w-scale -> swizzled ds_write (P1
//    shadow) into dbuf-2 (32KB). w read per-step from sWbT (8KB LDS).
//  - Per step: P0 {ds_read af0-3,b0-3 | issue A-regs(s+1), B(s+2)} bar
//    16 MFMA bar; P1 {ds_read af4-7 | vmcnt(2) scale+write A(s+1)} bar
//    16 MFMA lgkmcnt(0) bar. vmcnt(2) drains B(s+1)+A-regs (oldest), keeps
//    B(s+2) in flight. Never vmcnt(0) except s==126.
//  - Swizzle (BK=32): phys_chunk = chunk ^ ((row>>1)&3) -> <=2-way (free).
//  Kernel 1: R11 wave-per-token gating + cvt + Bt transpose (verbatim).

#define T_TOKENS 32768
#define DDIM 512
#define KDIM 4096
#define SLOT32 8192  // ushorts per 256x32 slot (16 KB)

typedef __attribute__((ext_vector_type(8))) short short8;
typedef __attribute__((ext_vector_type(4))) float floatx4;
typedef __bf16 bf16x2 __attribute__((ext_vector_type(2)));

__device__ __forceinline__ unsigned short f2bf(float f) {
    unsigned int u = __float_as_uint(f);
    u += 0x7FFFu + ((u >> 16) & 1u);   // RNE
    return (unsigned short)(u >> 16);
}

__device__ __forceinline__ unsigned int pk2(float a, float b) {
#if __has_builtin(__builtin_amdgcn_cvt_pk_bf16_f32)
    bf16x2 v = __builtin_amdgcn_cvt_pk_bf16_f32(a, b);
    return __builtin_bit_cast(unsigned int, v);
#else
    return (unsigned int)f2bf(a) | ((unsigned int)f2bf(b) << 16);
#endif
}

__device__ __forceinline__ void async_copy16(const void* g, void* l) {
    __builtin_amdgcn_global_load_lds(
        (const __attribute__((address_space(1))) void*)g,
        (__attribute__((address_space(3))) void*)l, 16, 0, 0);
}

// scale one packed bf16-pair by w (f32 math), repack
__device__ __forceinline__ unsigned int scale_pair(unsigned int u, float w) {
    float lo = __uint_as_float(u << 16) * w;
    float hi = __uint_as_float(u & 0xFFFF0000u) * w;
    return pk2(lo, hi);
}

// ------- Kernel 1 (fused): gating -> wbuf[T,8] + x->Xbf  |  build Bt -------
// blocks 0..511: gating+cvt (64 tokens each, wave-per-token). 512..1023: Bt.
// (verbatim from R11 — verified)
__global__ __launch_bounds__(256) void gating_cvt_bt(
    const float* __restrict__ x, const float* __restrict__ Wg,
    const float* __restrict__ bg, const float* __restrict__ Wt,
    const float* __restrict__ bt, float* __restrict__ wbuf,
    unsigned short* __restrict__ Xbf,
    const float* __restrict__ Wexp, unsigned short* __restrict__ Bt)
{
    const int tid = threadIdx.x;

    if (blockIdx.x >= 512) {
        __shared__ float tile[64][65];
        const int bb = blockIdx.x - 512;
        const int k0 = (bb & 63) * 64;
        const int n0 = (bb >> 6) * 64;
        const int r = tid >> 4, cq = tid & 15;
#pragma unroll
        for (int p = 0; p < 4; ++p) {
            const int rr = p * 16 + r;
            const float4 v = *(const float4*)(Wexp + (size_t)(k0 + rr) * 512 + n0 + cq * 4);
            tile[rr][cq * 4 + 0] = v.x;
            tile[rr][cq * 4 + 1] = v.y;
            tile[rr][cq * 4 + 2] = v.z;
            tile[rr][cq * 4 + 3] = v.w;
        }
        __syncthreads();
        const int rn = tid >> 2;
        const int kq = tid & 3;
        alignas(16) unsigned short buf[16];
#pragma unroll
        for (int j = 0; j < 16; ++j) buf[j] = f2bf(tile[kq * 16 + j][rn]);
        unsigned short* dst = Bt + (size_t)(n0 + rn) * KDIM + k0 + kq * 16;
        *(uint4*)(dst) = *(const uint4*)(buf);
        *(uint4*)(dst + 8) = *(const uint4*)(buf + 8);
        return;
    }

    const int wv = tid >> 6;
    const int lane = tid & 63;

    float4 wg[16];
    {
        const float4* wgp = (const float4*)(Wg + lane * 64);
#pragma unroll
        for (int c = 0; c < 16; ++c) wg[c] = wgp[c];
    }
    const float4 wt0 = *(const float4*)(Wt + lane * 8);
    const float4 wt1 = *(const float4*)(Wt + lane * 8 + 4);
    const float bgv[8] = {bg[0], bg[1], bg[2], bg[3], bg[4], bg[5], bg[6], bg[7]};
    const float btv = bt[0];

    for (int it = 0; it < 16; ++it) {
        const int t = blockIdx.x * 64 + wv * 16 + it;
        const float* xp = x + (size_t)t * 512 + lane * 8;
        const float4 a0 = *(const float4*)(xp);
        const float4 a1 = *(const float4*)(xp + 4);

        uint2 pk0, pk1;
        pk0.x = pk2(a0.x, a0.y);
        pk0.y = pk2(a0.z, a0.w);
        pk1.x = pk2(a1.x, a1.y);
        pk1.y = pk2(a1.z, a1.w);
        uint2* xd = (uint2*)(Xbf + (size_t)t * 512 + lane * 8);
        xd[0] = pk0;
        xd[1] = pk1;

        const float xv[8] = {a0.x, a0.y, a0.z, a0.w, a1.x, a1.y, a1.z, a1.w};
        const float wtv[8] = {wt0.x, wt0.y, wt0.z, wt0.w, wt1.x, wt1.y, wt1.z, wt1.w};
        float g[9];
#pragma unroll
        for (int e = 0; e < 9; ++e) g[e] = 0.f;
#pragma unroll
        for (int j = 0; j < 8; ++j) {
            const float4 wlo = wg[j * 2];
            const float4 whi = wg[j * 2 + 1];
            g[0] = fmaf(xv[j], wlo.x, g[0]);
            g[1] = fmaf(xv[j], wlo.y, g[1]);
            g[2] = fmaf(xv[j], wlo.z, g[2]);
            g[3] = fmaf(xv[j], wlo.w, g[3]);
            g[4] = fmaf(xv[j], whi.x, g[4]);
            g[5] = fmaf(xv[j], whi.y, g[5]);
            g[6] = fmaf(xv[j], whi.z, g[6]);
            g[7] = fmaf(xv[j], whi.w, g[7]);
            g[8] = fmaf(xv[j], wtv[j], g[8]);
        }
#pragma unroll
        for (int e = 0; e < 9; ++e) {
            g[e] += __shfl_xor(g[e], 1);
            g[e] += __shfl_xor(g[e], 2);
            g[e] += __shfl_xor(g[e], 4);
            g[e] += __shfl_xor(g[e], 8);
            g[e] += __shfl_xor(g[e], 16);
            g[e] += __shfl_xor(g[e], 32);
        }
        if (lane == 0) {
#pragma unroll
            for (int e = 0; e < 8; ++e) g[e] += bgv[e];
            g[8] += btv;
            float m = g[0];
#pragma unroll
            for (int e = 1; e < 8; ++e) m = fmaxf(m, g[e]);
            float s = 0.f;
            float p[8];
#pragma unroll
            for (int e = 0; e < 8; ++e) { p[e] = __expf(g[e] - m); s += p[e]; }
            const float inv = 1.f / s;
            const float thr = 0.25f / (1.f + __expf(-g[8]));
            float w8[8];
            float ws = 0.f;
#pragma unroll
            for (int e = 0; e < 8; ++e) {
                float a = p[e] * inv - thr;
                w8[e] = a > 0.f ? a : 0.f;
                ws += w8[e];
            }
            if (ws == 0.f) ws = 1.f;
            const float invw = 1.f / ws;
            float4 o0, o1;
            o0.x = w8[0] * invw; o0.y = w8[1] * invw; o0.z = w8[2] * invw; o0.w = w8[3] * invw;
            o1.x = w8[4] * invw; o1.y = w8[5] * invw; o1.z = w8[6] * invw; o1.w = w8[7] * invw;
            float4* op = (float4*)(wbuf + (size_t)t * 8);
            op[0] = o0;
            op[1] = o1;
        }
    }
}

// ------------- Kernel 2: 256x256 GEMM, BK=32, A-dbuf2 + B-ring3 ------------
// LDS element (row,k): chunk c=k/8 (0..3), phys p = c ^ ((row>>1)&3);
// addr = row*32 + p*8 + k%8 (ushorts).
__global__ __launch_bounds__(512, 2) void moe_gemm(
    const unsigned short* __restrict__ Xbf, const float* __restrict__ wbuf,
    const float* __restrict__ bexp, const unsigned short* __restrict__ Bt,
    float* __restrict__ out)
{
    __shared__ alignas(16) unsigned short Bs[3 * SLOT32];   // 48 KB
    __shared__ alignas(16) unsigned short Asl[2 * SLOT32];  // 32 KB
    __shared__ float sWbT[8 * 256];                         // 8 KB [e][row]

    const int tid = threadIdx.x;
    const int wave = tid >> 6;      // 0..7
    const int lane = tid & 63;
    const int wm = wave >> 2;       // 0..1: 128-row half
    const int wn = wave & 3;        // 0..3: 64-col quarter
    const int lm = lane & 15;
    const int lq = lane >> 4;
    // staging lane map: row-in-half srow, chunk pc; swizzle chunk cgk
    const int srow = wave * 16 + (lane >> 2);        // 0..127
    const int pc = lane & 3;
    const int cgk = pc ^ ((lane >> 3) & 3);          // == pc ^ ((srow>>1)&3)
    const int prd = lq ^ ((lm >> 1) & 3);            // read phys chunk

    // grid 256 = 128 t-tiles x 2 n-halves; XCD-paired (lin%8 = XCD)
    const int lin = blockIdx.x;
    const int g = lin & 7;
    const int j_ = lin >> 3;                  // 0..31
    const int t0 = (g * 16 + (j_ >> 1)) * 256;
    const int n0 = (j_ & 1) * 256;

    // sWbT[e][row] = wbuf[t0+row][e]
    {
        const int row = tid & 255, pr = tid >> 8;  // pr=0/1
        const float4 w4 = *(const float4*)(wbuf + (size_t)(t0 + row) * 8 + pr * 4);
        sWbT[(pr * 4 + 0) * 256 + row] = w4.x;
        sWbT[(pr * 4 + 1) * 256 + row] = w4.y;
        sWbT[(pr * 4 + 2) * 256 + row] = w4.z;
        sWbT[(pr * 4 + 3) * 256 + row] = w4.w;
    }

#define STAGE_B(s_, slot_)                                                      \
    {                                                                           \
        _Pragma("unroll")                                                       \
        for (int i = 0; i < 2; ++i)                                             \
            async_copy16(Bt + (size_t)(n0 + i * 128 + srow) * KDIM + (s_) * 32 + cgk * 8, \
                         Bs + (slot_) * SLOT32 + (i * 128 + wave * 16) * 32);   \
    }
#define LOADA(s_)                                                               \
    {                                                                           \
        const int d0_ = ((s_) & 15) << 5;                                       \
        _Pragma("unroll")                                                       \
        for (int i = 0; i < 2; ++i)                                             \
            ar[i] = *(const uint4*)(Xbf + (size_t)(t0 + i * 128 + srow) * 512 + d0_ + pc * 8); \
    }
#define AWRITE(s_)                                                              \
    {                                                                           \
        const int e1 = (s_) >> 4;                                               \
        _Pragma("unroll")                                                       \
        for (int i = 0; i < 2; ++i) {                                           \
            const float w = sWbT[e1 * 256 + i * 128 + srow];                    \
            uint4 o;                                                            \
            o.x = scale_pair(ar[i].x, w);                                       \
            o.y = scale_pair(ar[i].y, w);                                       \
            o.z = scale_pair(ar[i].z, w);                                       \
            o.w = scale_pair(ar[i].w, w);                                       \
            *(uint4*)(Asl + ((s_) & 1) * SLOT32 + (i * 128 + srow) * 32 + cgk * 8) = o; \
        }                                                                       \
    }
#define READ_AF(ih)                                                             \
    {                                                                           \
        _Pragma("unroll")                                                       \
        for (int ii = 0; ii < 4; ++ii) {                                        \
            const int row = wm * 128 + ((ih) * 4 + ii) * 16 + lm;               \
            af[ii] = *(const short8*)(Ab + row * 32 + prd * 8);                 \
        }                                                                       \
    }
#define READ_B()                                                                \
    {                                                                           \
        _Pragma("unroll")                                                       \
        for (int j = 0; j < 4; ++j) {                                           \
            const int row = wn * 64 + j * 16 + lm;                              \
            b[j] = *(const short8*)(Bb + row * 32 + prd * 8);                   \
        }                                                                       \
    }
#define MFMA_H(ih)                                                              \
    {                                                                           \
        __builtin_amdgcn_s_setprio(1);                                          \
        _Pragma("unroll")                                                       \
        for (int ii = 0; ii < 4; ++ii)                                          \
            _Pragma("unroll")                                                   \
            for (int j = 0; j < 4; ++j)                                         \
                acc[(ih) * 4 + ii][j] = __builtin_amdgcn_mfma_f32_16x16x32_bf16( \
                    af[ii], b[j], acc[(ih) * 4 + ii][j], 0, 0, 0);              \
        __builtin_amdgcn_s_setprio(0);                                          \
    }

    floatx4 acc[8][4];
#pragma unroll
    for (int i = 0; i < 8; ++i)
#pragma unroll
        for (int j = 0; j < 4; ++j) acc[i][j] = (floatx4){0.f, 0.f, 0.f, 0.f};

    uint4 ar[2];

    // ---- prologue ----
    LOADA(0);
    STAGE_B(0, 0);
    STAGE_B(1, 1);
    __syncthreads();          // drains vm+lgkm (sWbT writes, A(0) regs, B(0),B(1))
    AWRITE(0);                // scale A(0) into Asl[0]
    asm volatile("s_waitcnt lgkmcnt(0)" ::: "memory");
    __builtin_amdgcn_s_barrier();

    int sl = 0;  // B slot of step s
    for (int s = 0; s < 128; ++s) {
        const unsigned short* Ab = Asl + (s & 1) * SLOT32;
        const unsigned short* Bb = Bs + sl * SLOT32;
        const int sl2 = (sl == 0) ? 2 : sl - 1;  // (sl+2)%3
        short8 af[4], b[4];

        // ---- P0: read af0-3 + b0-3 ; issue A(s+1) regs + B(s+2) ----
        READ_AF(0);
        READ_B();
        if (s < 127) LOADA(s + 1);
        if (s < 126) STAGE_B(s + 2, sl2);
        __builtin_amdgcn_s_barrier();
        MFMA_H(0);
        __builtin_amdgcn_s_barrier();

        // ---- P1: read af4-7 ; drain older loads, scale+write A(s+1) ----
        READ_AF(1);
        if (s < 126) {
            asm volatile("s_waitcnt vmcnt(2)" ::: "memory");  // drains B(s+1)+A regs
        } else if (s == 126) {
            asm volatile("s_waitcnt vmcnt(0)" ::: "memory");
        }
        if (s < 127) AWRITE(s + 1);
        __builtin_amdgcn_s_barrier();
        MFMA_H(1);
        if (s < 127) asm volatile("s_waitcnt lgkmcnt(0)" ::: "memory");
        __builtin_amdgcn_s_barrier();

        sl = (sl == 2) ? 0 : sl + 1;
    }

    // ---- epilogue: out = acc + sum_e w[t,e]*b_exp[e,col] (R10-verified) ----
    float bc[4][8];
#pragma unroll
    for (int j = 0; j < 4; ++j) {
        const int col = n0 + wn * 64 + j * 16 + lm;
#pragma unroll
        for (int e = 0; e < 8; ++e) bc[j][e] = bexp[e * 512 + col];
    }
#pragma unroll
    for (int i = 0; i < 8; ++i)
#pragma unroll
        for (int r = 0; r < 4; ++r) {
            const int rowl = wm * 128 + i * 16 + lq * 4 + r;
            const float4 w0 = *(const float4*)(wbuf + (size_t)(t0 + rowl) * 8);
            const float4 w1 = *(const float4*)(wbuf + (size_t)(t0 + rowl) * 8 + 4);
            float* op = out + (size_t)(t0 + rowl) * 512 + n0 + wn * 64 + lm;
#pragma unroll
            for (int j = 0; j < 4; ++j) {
                float bias = w0.x * bc[j][0];
                bias = fmaf(w0.y, bc[j][1], bias);
                bias = fmaf(w0.z, bc[j][2], bias);
                bias = fmaf(w0.w, bc[j][3], bias);
                bias = fmaf(w1.x, bc[j][4], bias);
                bias = fmaf(w1.y, bc[j][5], bias);
                bias = fmaf(w1.z, bc[j][6], bias);
                bias = fmaf(w1.w, bc[j][7], bias);
                op[j * 16] = acc[i][j][r] + bias;
            }
        }
#undef STAGE_B
#undef LOADA
#undef AWRITE
#undef READ_AF
#undef READ_B
#undef MFMA_H
}

extern "C" void kernel_launch(void* const* d_in, const int* in_sizes, int n_in,
                              void* d_out, int out_size, void* d_ws, size_t ws_size,
                              hipStream_t stream) {
    const float* x   = (const float*)d_in[0];
    const float* Wg  = (const float*)d_in[1];
    const float* bg  = (const float*)d_in[2];
    const float* Wt  = (const float*)d_in[3];
    const float* bt  = (const float*)d_in[4];
    const float* Wex = (const float*)d_in[5];
    const float* bex = (const float*)d_in[6];
    float* out = (float*)d_out;

    // ws layout: Xbf bf16 [32768][512] = 32 MB; Bt bf16 [512][4096] = 4 MB;
    //            wbuf fp32 [32768][8] = 1 MB.  Total 37 MB.
    unsigned short* Xbf = (unsigned short*)d_ws;
    unsigned short* Bt  = (unsigned short*)((char*)d_ws + (size_t)T_TOKENS * DDIM * 2);
    float* wbuf = (float*)((char*)d_ws + (size_t)T_TOKENS * DDIM * 2
                                       + (size_t)DDIM * KDIM * 2);

    gating_cvt_bt<<<1024, 256, 0, stream>>>(x, Wg, bg, Wt, bt, wbuf, Xbf, Wex, Bt);
    moe_gemm<<<256, 512, 0, stream>>>(Xbf, wbuf, bex, Bt, out);
}